// Round 4
// baseline (432.092 us; speedup 1.0000x reference)
//
#include <hip/hip_runtime.h>

typedef unsigned int u32;
typedef unsigned short u16;

#define B_   16
#define C_   128
#define SEQ_ 16384
#define K_   64
#define TS_  64    // samples per tile
#define NT_  4     // tiles per block -> 256 samples/block

// ---- workspace layout (float offsets) ----
constexpr int OFF_EACC = 0;            // [B][K][C] = 131072 floats (atomic accum)
constexpr int OFF_ASUM = 131072;       // [B][K]    = 1024
constexpr int OFF_CWT  = 132096;       // [C][K] bf16 packed = 4096 floats of storage
constexpr int OFF_SM   = 136192;       // [K] = 64
constexpr int OFF_SMC2 = 136256;       // [K] = 64  (sm[k]*||cw_k||^2)
constexpr int OFF_SCALE= 136320;       // [B][C] = 2048
// total 138368 floats = 553,472 B of ws

__device__ __forceinline__ float bf_lo(u32 u) { return __uint_as_float(u << 16); }
__device__ __forceinline__ float bf_hi(u32 u) { return __uint_as_float(u & 0xFFFF0000u); }
__device__ __forceinline__ u16 f2bf(float f) {
    u32 b = __float_as_uint(f);
    return (u16)((b + 0x7FFFu + ((b >> 16) & 1u)) >> 16);   // RNE
}
// NaN -> -1e4 (then clamp): fmaxf(NaN,a)=a, fminf then is a no-op
__device__ __forceinline__ float scrub(float v) {
    return fminf(fmaxf(v, -1.0e4f), 1.0e4f);
}

// ---------------- k0: prep tables (all-fp32 inputs) ----------------
__global__ void k0_prep(const float* __restrict__ cw, const float* __restrict__ sm,
                        float* __restrict__ ws) {
    const int t = threadIdx.x;  // 256
    u16* cwt = (u16*)(ws + OFF_CWT);
    for (int i = 0; i < 32; ++i) {
        int idx = i * 256 + t;            // 8192 = 64*128
        int k = idx >> 7, c = idx & 127;
        cwt[c * K_ + k] = f2bf(cw[idx]);  // transposed bf16 (dot input only)
    }
    if (t < K_) {
        float s2 = 0.f;
        for (int c = 0; c < C_; ++c) { float f = cw[t * C_ + c]; s2 += f * f; }
        float smv = sm[t];
        ws[OFF_SM + t] = smv;
        ws[OFF_SMC2 + t] = smv * s2;      // fp32-exact ||cw||^2 path
    }
}

// ---------------- k1: soft-assign encode + aggregate ----------------
// grid = B * (SEQ/(TS*NT)) = 16*64 = 1024 blocks, 256 threads
__global__ __launch_bounds__(256, 2)
void k1_encode(const float* __restrict__ xg, float* ws) {
    __shared__ __align__(16) float xt_f[C_][68];    // x tile fp32: [c][s], stride 68 (16B-aligned rows)
    __shared__ __align__(16) float a_s[TS_][68];    // dot -> softmax: [s][k], pad 64->68
    __shared__ __align__(16) u32   cwt32[C_][32];   // cw^T bf16 pairs: [c][k/2]
    __shared__ float x2_s[TS_];
    __shared__ float sm_s[K_], smc2_s[K_];

    const int t = threadIdx.x;
    const int bid = blockIdx.x;
    const int b = bid >> 6;                       // 64 chunks per batch
    const int s_base = (bid & 63) * (TS_ * NT_);  // 256-sample chunk

    // stage cw^T + sm tables (written by k0)
    {
        const u32* src = (const u32*)(ws + OFF_CWT);
        u32* dst = &cwt32[0][0];
        for (int i = 0; i < 16; ++i) dst[i * 256 + t] = src[i * 256 + t];
        if (t < K_) { sm_s[t] = ws[OFF_SM + t]; smc2_s[t] = ws[OFF_SMC2 + t]; }
    }

    const int sq = t & 15;   // phase B: s-group (s0=4sq) | phase D: c-group (c=sq+16j)
    const int kq = t >> 4;   // k-group (k0=4kq) in both phases
    float acc[4][8];
    for (int kj = 0; kj < 4; ++kj)
        for (int j = 0; j < 8; ++j) acc[kj][j] = 0.f;
    float asacc[4] = {0.f, 0.f, 0.f, 0.f};

    const float4* xg4 = (const float4*)xg;

    for (int tile = 0; tile < NT_; ++tile) {
        const int st = s_base + tile * TS_;
        __syncthreads();   // xt/a_s free from previous tile; staging visible on tile 0
        // ---- phase A: global x tile -> LDS (fp32, float4) ----
        for (int i = 0; i < 8; ++i) {
            int p = i * 256 + t;          // 2048 float4 = 128 rows x 16 float4
            int c = p >> 4;
            int q = p & 15;
            float4 v = xg4[(size_t)(b * C_ + c) * (SEQ_ / 4) + (st >> 2) + q];
            *(float4*)&xt_f[c][q * 4] = v;
        }
        __syncthreads();
        // ---- phase B: dot = x . cw_k  (4s x 4k per thread), fused ||x||^2 ----
        float dot[4][4] = {{0.f,0.f,0.f,0.f},{0.f,0.f,0.f,0.f},{0.f,0.f,0.f,0.f},{0.f,0.f,0.f,0.f}};
        float xsq[4] = {0.f, 0.f, 0.f, 0.f};
        for (int c = 0; c < C_; ++c) {
            float4 xv = *(const float4*)&xt_f[c][sq * 4];
            uint2 wu = *(const uint2*)&cwt32[c][kq * 2];
            float xa[4] = { xv.x, xv.y, xv.z, xv.w };
            float wa[4] = { bf_lo(wu.x), bf_hi(wu.x), bf_lo(wu.y), bf_hi(wu.y) };
            for (int sj = 0; sj < 4; ++sj)
                for (int kj = 0; kj < 4; ++kj)
                    dot[sj][kj] += xa[sj] * wa[kj];
            if (kq == 0) {
                for (int sj = 0; sj < 4; ++sj) xsq[sj] += xa[sj] * xa[sj];
            }
        }
        // store raw dot (float4, 16B aligned: row stride 68*4=272B = 16*17)
        {
            const int s0 = sq * 4, k0 = kq * 4;
            for (int sj = 0; sj < 4; ++sj) {
                float4 dv;
                dv.x = dot[sj][0]; dv.y = dot[sj][1]; dv.z = dot[sj][2]; dv.w = dot[sj][3];
                *(float4*)&a_s[s0 + sj][k0] = dv;
            }
        }
        if (kq == 0) {
            for (int sj = 0; sj < 4; ++sj) x2_s[sq * 4 + sj] = xsq[sj];
        }
        __syncthreads();
        // ---- phase C: per-row softmax (thread t < 64 owns sample row t) ----
        if (t < TS_) {
            float xx = x2_s[t];
            float m = -1.0e30f;
            for (int k = 0; k < K_; ++k) {
                float d = a_s[t][k];
                float lv = sm_s[k] * (xx - 2.f * d) + smc2_s[k];
                lv = scrub(lv);                 // no-op on sane data
                a_s[t][k] = lv;
                m = fmaxf(m, lv);
            }
            float ssum = 0.f;
            for (int k = 0; k < K_; ++k) {
                float ev = __expf(a_s[t][k] - m);
                a_s[t][k] = ev;
                ssum += ev;
            }
            float inv = 1.f / ssum;             // ssum >= 1 (max term = 1)
            for (int k = 0; k < K_; ++k) a_s[t][k] *= inv;
        }
        __syncthreads();
        // ---- phase D: acc[k][c] += sum_s a[s][k] * x[s][c]  (4k x 8c per thread) ----
        for (int s = 0; s < TS_; ++s) {
            float4 av = *(const float4*)&a_s[s][kq * 4];
            float a0[4] = {av.x, av.y, av.z, av.w};
            for (int j = 0; j < 8; ++j) {
                float xv = xt_f[sq + 16 * j][s];
                for (int kj = 0; kj < 4; ++kj)
                    acc[kj][j] += a0[kj] * xv;
            }
            if (sq == 0) {
                for (int kj = 0; kj < 4; ++kj) asacc[kj] += a0[kj];
            }
        }
    }
    // ---- flush partial sums ----
    float* eacc = ws + OFF_EACC;
    const int k0 = kq * 4;
    for (int kj = 0; kj < 4; ++kj)
        for (int j = 0; j < 8; ++j)
            atomicAdd(&eacc[(b * K_ + k0 + kj) * C_ + sq + 16 * j], acc[kj][j]);
    if (sq == 0) {
        for (int kj = 0; kj < 4; ++kj)
            atomicAdd(&ws[OFF_ASUM + b * K_ + k0 + kj], asacc[kj]);
    }
}

// ---------------- k2: BN + relu-mean + FC + sigmoid (single block) ----------------
__global__ __launch_bounds__(1024)
void k2_bn_fc(const float* __restrict__ cw,
              const float* __restrict__ bnw, const float* __restrict__ bnb,
              const float* __restrict__ fcw, const float* __restrict__ fcb,
              float* ws) {
    __shared__ float fcw_s[C_][C_ + 1];  // fp32, pad 129 for bank spread
    __shared__ float enorm_s[B_ * C_];
    __shared__ float redA[K_][16], redB[K_][16];
    __shared__ float scale_k[K_], bias_k[K_];
    const int t = threadIdx.x;  // 1024
    const float* eacc = ws + OFF_EACC;
    const float* asum = ws + OFF_ASUM;
    for (int i = 0; i < 16; ++i) {
        int idx = i * 1024 + t;           // 16384
        fcw_s[idx >> 7][idx & 127] = fcw[idx];
    }
    // per-k batch stats over (b,c) = 2048 values
    {
        int k = t >> 4, part = t & 15;
        float sv = 0.f, sq2 = 0.f;
        for (int i = 0; i < 128; ++i) {
            int flat = part + (i << 4);
            int bb = flat >> 7, c = flat & 127;
            float e = eacc[(bb * K_ + k) * C_ + c] - asum[bb * K_ + k] * cw[k * C_ + c];
            sv += e; sq2 += e * e;
        }
        redA[k][part] = sv; redB[k][part] = sq2;
    }
    __syncthreads();
    if (t < K_) {
        float sv = 0.f, sq2 = 0.f;
        for (int p = 0; p < 16; ++p) { sv += redA[t][p]; sq2 += redB[t][p]; }
        float mean = sv * (1.f / 2048.f);
        float var  = sq2 * (1.f / 2048.f) - mean * mean;
        float rstd = rsqrtf(fmaxf(var, 0.f) + 1e-5f);
        float g = bnw[t] * rstd;
        scale_k[t] = g;
        bias_k[t]  = bnb[t] - mean * g;
    }
    __syncthreads();
    // e_norm[b][c] = mean_k relu(bn(e))
    for (int r = 0; r < 2; ++r) {
        int u = r * 1024 + t;
        int bb = u >> 7, c = u & 127;
        float s = 0.f;
        for (int k = 0; k < K_; ++k) {
            float e = eacc[(bb * K_ + k) * C_ + c] - asum[bb * K_ + k] * cw[k * C_ + c];
            float bnv = e * scale_k[k] + bias_k[k];
            bnv = fminf(fmaxf(bnv, 0.f), 1.0e6f);       // relu (+ NaN scrub, no-op sane)
            s += bnv;
        }
        enorm_s[u] = s * (1.f / 64.f);
    }
    __syncthreads();
    // scale[b][c] = sigmoid(enorm[b] . fc_w[c] + fc_b[c])
    for (int r = 0; r < 2; ++r) {
        int u = r * 1024 + t;
        int bb = u >> 7, c = u & 127;
        float accv = fcb[c];
        for (int cc = 0; cc < C_; ++cc)
            accv += enorm_s[(bb << 7) + cc] * fcw_s[c][cc];
        ws[OFF_SCALE + u] = 1.f / (1.f + __expf(-accv));
    }
}

// ---------------- k3: out = x * scale[b,c]  (fp32 stream) ----------------
__global__ __launch_bounds__(256)
void k3_scale(const float4* __restrict__ xg, float4* __restrict__ outg,
              const float* __restrict__ ws) {
    const int bc = blockIdx.x;                 // b*128 + c
    const float sc = ws[OFF_SCALE + bc];
    const float4* xr = xg + (size_t)bc * (SEQ_ / 4);
    float4* orow = outg + (size_t)bc * (SEQ_ / 4);
    const int t = threadIdx.x;
    for (int i = 0; i < SEQ_ / 4 / 256; ++i) {  // 16 iters
        float4 v = xr[i * 256 + t];
        v.x *= sc; v.y *= sc; v.z *= sc; v.w *= sc;
        orow[i * 256 + t] = v;
    }
}

extern "C" void kernel_launch(void* const* d_in, const int* in_sizes, int n_in,
                              void* d_out, int out_size, void* d_ws, size_t ws_size,
                              hipStream_t stream) {
    const float* x   = (const float*)d_in[0];   // (16,128,1,16384) fp32
    const float* cw  = (const float*)d_in[1];   // (64,128)
    const float* sm  = (const float*)d_in[2];   // (64,)
    const float* bnw = (const float*)d_in[3];   // (64,)
    const float* bnb = (const float*)d_in[4];   // (64,)
    const float* fcw = (const float*)d_in[5];   // (128,128)
    const float* fcb = (const float*)d_in[6];   // (128,)
    float* ws = (float*)d_ws;

    hipMemsetAsync(ws, 0, (size_t)(OFF_ASUM + B_ * K_) * sizeof(float), stream);
    k0_prep<<<1, 256, 0, stream>>>(cw, sm, ws);
    k1_encode<<<B_ * (SEQ_ / (TS_ * NT_)), 256, 0, stream>>>(x, ws);
    k2_bn_fc<<<1, 1024, 0, stream>>>(cw, bnw, bnb, fcw, fcb, ws);
    k3_scale<<<B_ * C_, 256, 0, stream>>>((const float4*)x, (float4*)d_out, ws);
}